// Round 10
// baseline (135.552 us; speedup 1.0000x reference)
//
#include <hip/hip_runtime.h>

#define DD 160
#define HH 160
#define WW 160
#define VOL (DD * HH * WW)   // per-batch volume = 4,096,000
#define PLANE (HH * WW)      // 25,600
#define NB 2

// pass 1a: D-sum streaming (4 columns/thread, add/sub window)
#define CH 20                // d-centers per block
#define NDSP (DD / CH)       // 8
#define DSBLK (PLANE / 1024) // 25 quad-tiles (256 thr * 4 cols)
#define NDSUM (DSBLK * NDSP * NB)  // 400 blocks

// pass 1b: grad
#define GCHD 20
#define GBLK (NB * 3 * (DD / GCHD) * HH * (WW / 4) / 256)   // 1200 blocks

// pass 2: WH + cc
#define HT 16
#define HS (HT + 8)          // 24 staged rows
#define LDWH 168             // LDS row stride (halves), 336B
#define WHBLK ((HH / HT) * DD * NB)   // 3200

// fields layout: AoS quad-records. record r = (b*DD+d)*6400 + (h*40 + w/4),
// holds 5 x h4 (40 B contiguous): elem offset in halves = r*20 + f*4.
typedef _Float16 h8 __attribute__((ext_vector_type(8)));
typedef _Float16 h4 __attribute__((ext_vector_type(4)));

// ---------------------------------------------------------------------------
// Pass 1 (merged): blocks [0, NDSUM): D-direction box sums of the 5 moment
// fields, add/sub sliding window on raw m,f; AoS 40B-record stores (single
// contiguous write stream per wave). Blocks [NDSUM, ...): flow L1 gradient.
// ---------------------------------------------------------------------------
__global__ __launch_bounds__(256) void stream_pass(const float* __restrict__ mv,
                                                   const float* __restrict__ fx,
                                                   const float* __restrict__ fl,
                                                   _Float16* __restrict__ fields,
                                                   float* __restrict__ pg) {
    const int bx  = blockIdx.x;
    const int tid = threadIdx.x;

    if (bx < NDSUM) {
        const int qt  = bx % DSBLK;          // quad-tile
        const int rem = bx / DSBLK;
        const int dsp = rem % NDSP;
        const int b   = rem / NDSP;
        const int q4  = qt * 256 + tid;      // quad index 0..6399
        const int hw  = q4 * 4;
        const int c0  = dsp * CH;
        const int cend = c0 + CH;

        const float* pm = mv + (size_t)b * VOL + hw;
        const float* pf = fx + (size_t)b * VOL + hw;

        float4 s0 = {0,0,0,0}, s1 = {0,0,0,0}, s2 = {0,0,0,0},
               s3 = {0,0,0,0}, s4 = {0,0,0,0};

#define ACC4(m4, f4, sgn)                                              \
        s0.x sgn m4.x; s0.y sgn m4.y; s0.z sgn m4.z; s0.w sgn m4.w;    \
        s1.x sgn f4.x; s1.y sgn f4.y; s1.z sgn f4.z; s1.w sgn f4.w;    \
        s2.x sgn m4.x * m4.x; s2.y sgn m4.y * m4.y;                    \
        s2.z sgn m4.z * m4.z; s2.w sgn m4.w * m4.w;                    \
        s3.x sgn f4.x * f4.x; s3.y sgn f4.y * f4.y;                    \
        s3.z sgn f4.z * f4.z; s3.w sgn f4.w * f4.w;                    \
        s4.x sgn m4.x * f4.x; s4.y sgn m4.y * f4.y;                    \
        s4.z sgn m4.z * f4.z; s4.w sgn m4.w * f4.w;

        {   // warm-up: planes [c0-4, c0+4] clipped
            int lo = c0 - 4 > 0 ? c0 - 4 : 0;
            int hi = c0 + 4 < DD - 1 ? c0 + 4 : DD - 1;
            for (int dd = lo; dd <= hi; ++dd) {
                float4 m4 = *(const float4*)(pm + (size_t)dd * PLANE);
                float4 f4 = *(const float4*)(pf + (size_t)dd * PLANE);
                ACC4(m4, f4, +=)
            }
        }

        for (int d = c0; d < cend; ++d) {
            // AoS record: 40 contiguous bytes for this quad's 5 fields
            _Float16* o = fields + ((size_t)(b * DD + d) * 6400 + q4) * 20;
            h4 t;
            t.x = (_Float16)s0.x; t.y = (_Float16)s0.y; t.z = (_Float16)s0.z; t.w = (_Float16)s0.w;
            *(h4*)(o + 0)  = t;
            t.x = (_Float16)s1.x; t.y = (_Float16)s1.y; t.z = (_Float16)s1.z; t.w = (_Float16)s1.w;
            *(h4*)(o + 4)  = t;
            t.x = (_Float16)s2.x; t.y = (_Float16)s2.y; t.z = (_Float16)s2.z; t.w = (_Float16)s2.w;
            *(h4*)(o + 8)  = t;
            t.x = (_Float16)s3.x; t.y = (_Float16)s3.y; t.z = (_Float16)s3.z; t.w = (_Float16)s3.w;
            *(h4*)(o + 12) = t;
            t.x = (_Float16)s4.x; t.y = (_Float16)s4.y; t.z = (_Float16)s4.z; t.w = (_Float16)s4.w;
            *(h4*)(o + 16) = t;

            if (d + 1 < cend) {
                if (d + 5 < DD) {
                    float4 m4 = *(const float4*)(pm + (size_t)(d + 5) * PLANE);
                    float4 f4 = *(const float4*)(pf + (size_t)(d + 5) * PLANE);
                    ACC4(m4, f4, +=)
                }
                if (d - 4 >= 0) {
                    float4 m4 = *(const float4*)(pm + (size_t)(d - 4) * PLANE);
                    float4 f4 = *(const float4*)(pf + (size_t)(d - 4) * PLANE);
                    ACC4(m4, f4, -=)
                }
            }
        }
#undef ACC4
        return;
    }

    // ---- grad: L1 forward diffs on flow, d-walking float4 chunks ----
    const int gid = (bx - NDSUM) * 256 + tid;    // 0..307199
    const int w4  = gid % 40;
    int t = gid / 40;
    const int h  = t % HH;  t /= HH;
    const int dc = t % (DD / GCHD); t /= (DD / GCHD);
    const int bc = t;                            // 0..5
    const int d0 = dc * GCHD;
    const int w  = w4 * 4;

    const float* base = fl + (size_t)bc * VOL;
    float acc = 0.f;
    float4 v = *(const float4*)(base + ((size_t)d0 * HH + h) * WW + w);
    for (int d = d0; d < d0 + GCHD; ++d) {
        const float* pd = base + ((size_t)d * HH + h) * WW + w;
        float4 vn = v;
        if (d < DD - 1) {
            vn = *(const float4*)(pd + PLANE);
            acc += fabsf(vn.x - v.x) + fabsf(vn.y - v.y) +
                   fabsf(vn.z - v.z) + fabsf(vn.w - v.w);
        }
        if (h < HH - 1) {
            float4 vh = *(const float4*)(pd + WW);
            acc += fabsf(vh.x - v.x) + fabsf(vh.y - v.y) +
                   fabsf(vh.z - v.z) + fabsf(vh.w - v.w);
        }
        acc += fabsf(v.y - v.x) + fabsf(v.z - v.y) + fabsf(v.w - v.z);
        if (w < WW - 4) acc += fabsf(pd[4] - v.w);
        v = vn;
    }

    for (int o = 32; o > 0; o >>= 1) acc += __shfl_down(acc, o, 64);
    __shared__ float red[4];
    int lane = tid & 63, wid = tid >> 6;
    if (lane == 0) red[wid] = acc;
    __syncthreads();
    if (tid == 0) pg[bx - NDSUM] = red[0] + red[1] + red[2] + red[3];
}

// ---------------------------------------------------------------------------
// Pass 2: W+H box sums of the 5 D-summed fields + per-voxel cc + reduction.
// Block: 512 thr, output tile 16h x 160w at one (d, b). Grid (10, 160, 2).
// Stage A reads the AoS records: 160 contiguous bytes per thread.
// ---------------------------------------------------------------------------
__global__ __launch_bounds__(512, 6) void ncc_whcc(const _Float16* __restrict__ fields,
                                                   float* __restrict__ partial) {
    __shared__ _Float16 ws[5][HS][LDWH];
    __shared__ float red[8];

    const int hx  = blockIdx.x;        // 0..9
    const int d   = blockIdx.y;        // 0..159
    const int b   = blockIdx.z;        // 0..1
    const int h0  = hx * HT;
    const int tid = threadIdx.x;

    if (tid < 480) {
        const int r  = tid / 20;       // 0..23 staged row
        const int s  = tid - r * 20;   // 0..19 octet
        const int h  = h0 - 4 + r;
        const int w0 = 8 * s;
        const bool rowok = (unsigned)h < (unsigned)HH;
        // row record base (in halves): quad q at row h -> base + q*20
        const size_t rowrec = ((size_t)(b * DD + d) * 6400 + (size_t)h * 40) * 20;

#pragma unroll
        for (int f = 0; f < 5; ++f) {
            float v[16];
#pragma unroll
            for (int i = 0; i < 16; ++i) v[i] = 0.f;
            if (rowok) {
                const int q0 = 2 * s;          // quad of w0
                if (s > 0) {
                    h4 a = *(const h4*)(fields + rowrec + (size_t)(q0 - 1) * 20 + f * 4);
                    v[0] = (float)a.x; v[1] = (float)a.y; v[2] = (float)a.z; v[3] = (float)a.w;
                }
                h4 a1 = *(const h4*)(fields + rowrec + (size_t)q0 * 20 + f * 4);
                v[4] = (float)a1.x; v[5] = (float)a1.y; v[6] = (float)a1.z; v[7] = (float)a1.w;
                h4 a2 = *(const h4*)(fields + rowrec + (size_t)(q0 + 1) * 20 + f * 4);
                v[8] = (float)a2.x; v[9] = (float)a2.y; v[10] = (float)a2.z; v[11] = (float)a2.w;
                if (s < 19) {
                    h4 a3 = *(const h4*)(fields + rowrec + (size_t)(q0 + 2) * 20 + f * 4);
                    v[12] = (float)a3.x; v[13] = (float)a3.y; v[14] = (float)a3.z; v[15] = (float)a3.w;
                }
            }
            float o[8];
            float sum = 0.f;
#pragma unroll
            for (int i = 0; i < 9; ++i) sum += v[i];
            o[0] = sum;
#pragma unroll
            for (int k = 1; k < 8; ++k) {
                sum += v[k + 8] - v[k - 1];
                o[k] = sum;
            }
            h8 pk;
#pragma unroll
            for (int j = 0; j < 8; ++j) pk[j] = (_Float16)o[j];
            *(h8*)&ws[f][r][w0] = pk;
        }
    }
    __syncthreads();

    float acc = 0.f;
    if (tid < 320) {
        const int ro  = tid / 20;      // 0..15 output row
        const int oct = tid - ro * 20; // 0..19
        const int w   = 8 * oct;

        float s0[8], s1[8], s2[8], s3[8], s4[8];
#pragma unroll
        for (int j = 0; j < 8; ++j) { s0[j]=0.f; s1[j]=0.f; s2[j]=0.f; s3[j]=0.f; s4[j]=0.f; }
#pragma unroll
        for (int t = 0; t < 9; ++t) {
            h8 v0 = *(const h8*)&ws[0][ro + t][w];
            h8 v1 = *(const h8*)&ws[1][ro + t][w];
            h8 v2 = *(const h8*)&ws[2][ro + t][w];
            h8 v3 = *(const h8*)&ws[3][ro + t][w];
            h8 v4 = *(const h8*)&ws[4][ro + t][w];
#pragma unroll
            for (int j = 0; j < 8; ++j) {
                s0[j] += (float)v0[j]; s1[j] += (float)v1[j];
                s2[j] += (float)v2[j]; s3[j] += (float)v3[j];
                s4[j] += (float)v4[j];
            }
        }
        const float inv_win = 1.0f / 729.0f;
#pragma unroll
        for (int j = 0; j < 8; ++j) {
            float cross = fmaf(-(s0[j] * s1[j]), inv_win, s4[j]);
            float pv = fmaxf(fmaf(-(s0[j] * s0[j]), inv_win, s2[j]), 0.f);
            float tv = fmaxf(fmaf(-(s1[j] * s1[j]), inv_win, s3[j]), 0.f);
            float cc = cross * cross / (pv * tv + 0.001f);
            acc += fminf(fmaxf(cc, 0.f), 1.f);
        }
    }

    for (int o = 32; o > 0; o >>= 1) acc += __shfl_down(acc, o, 64);
    int lane = tid & 63, wid = tid >> 6;
    if (lane == 0) red[wid] = acc;
    __syncthreads();
    if (tid == 0) {
        float r8 = 0.f;
#pragma unroll
        for (int i = 0; i < 8; ++i) r8 += red[i];
        partial[((size_t)b * DD + d) * (HH / HT) + hx] = r8;
    }
}

// ---------------------------------------------------------------------------
// Pass 3: final deterministic reduction of partials -> scalar loss
// ---------------------------------------------------------------------------
__global__ __launch_bounds__(256) void finalize(const float* __restrict__ pcc, int ncc,
                                                const float* __restrict__ pg, int ng,
                                                float* __restrict__ out) {
    __shared__ float red[4];
    int lane = threadIdx.x & 63, wid = threadIdx.x >> 6;

    float a = 0.f;
    for (int i = threadIdx.x; i < ncc; i += 256) a += pcc[i];
    for (int o = 32; o > 0; o >>= 1) a += __shfl_down(a, o, 64);
    if (lane == 0) red[wid] = a;
    __syncthreads();
    float asum = red[0] + red[1] + red[2] + red[3];
    __syncthreads();

    float g = 0.f;
    for (int i = threadIdx.x; i < ng; i += 256) g += pg[i];
    for (int o = 32; o > 0; o >>= 1) g += __shfl_down(g, o, 64);
    if (lane == 0) red[wid] = g;
    __syncthreads();
    float gsum = red[0] + red[1] + red[2] + red[3];

    if (threadIdx.x == 0) {
        float sim = 1.0f - asum / 8192000.0f;          // mean over (2,1,160,160,160)
        float reg = gsum / 73267200.0f;                // 3 * (2*3*159*160*160)
        out[0] = sim + reg;
    }
}

// ---------------------------------------------------------------------------
extern "C" void kernel_launch(void* const* d_in, const int* in_sizes, int n_in,
                              void* d_out, int out_size, void* d_ws, size_t ws_size,
                              hipStream_t stream) {
    const float* moved  = (const float*)d_in[0];
    const float* fixedp = (const float*)d_in[1];
    const float* flow   = (const float*)d_in[2];
    float* out = (float*)d_out;

    _Float16* fields = (_Float16*)d_ws;                   // NB*5*VOL fp16 AoS (81.9 MB)
    float* pcc = (float*)(fields + (size_t)NB * 5 * VOL); // WHBLK floats
    float* pg  = pcc + WHBLK;                             // GBLK floats

    stream_pass<<<NDSUM + GBLK, 256, 0, stream>>>(moved, fixedp, flow, fields, pg);
    ncc_whcc<<<dim3(HH / HT, DD, NB), 512, 0, stream>>>(fields, pcc);
    finalize<<<1, 256, 0, stream>>>(pcc, WHBLK, pg, GBLK, out);
}

// Round 11
// 130.695 us; speedup vs baseline: 1.0372x; 1.0372x over previous
//
#include <hip/hip_runtime.h>

#define DD 160
#define HH 160
#define WW 160
#define VOL (DD * HH * WW)   // per-batch volume = 4,096,000
#define PLANE (HH * WW)      // 25,600
#define NB 2

// fused NCC tiling
#define HT 16                // output h-rows per block
#define WT 16                // output w-cols per block
#define DC 20                // output d-centers per block
#define NHT (HH / HT)        // 10
#define NWT (WW / WT)        // 10
#define NDC (DD / DC)        // 8
#define NCCB (NHT * NWT * NDC * NB)   // 1600 NCC blocks

// grad
#define GCHD 20
#define GBLK (NB * 3 * (DD / GCHD) * HH * (WW / 4) / 256)   // 1200 blocks

typedef _Float16 h4 __attribute__((ext_vector_type(4)));

// ---------------------------------------------------------------------------
// Fused kernel. Blocks [0, NCCB): full NCC for a 16h x 16w x 20d output tile.
//   Walk planes p; per round: stage A { cc: add ring[(p-1)%9], emit center
//   p-5, sub ring[p%9]  ||  W-threads: raw plane p -> W-sums in ws } barrier;
//   stage B { H-threads: ws -> H-sums -> ring[p%9] } barrier.
//   Ring slot overwritten == plane leaving the window (9-deep ring).
//   No intermediate global buffer at all; only per-block partial out.
// Blocks [NCCB, NCCB+GBLK): flow L1-gradient reduction.
// ---------------------------------------------------------------------------
__global__ __launch_bounds__(256) void fused(const float* __restrict__ mv,
                                             const float* __restrict__ fx,
                                             const float* __restrict__ fl,
                                             float* __restrict__ pcc,
                                             float* __restrict__ pg) {
    __shared__ float    ws[5][HT + 8][WT + 4];     // [5][24][20] fp32  9.6 KB
    __shared__ _Float16 ring[9][5][HT][WT + 4];    // [9][5][16][20]   28.8 KB
    __shared__ float    red[4];

    const int bx  = blockIdx.x;
    const int tid = threadIdx.x;

    if (bx < NCCB) {
        int tt = bx;
        const int ht  = tt % NHT; tt /= NHT;
        const int wt  = tt % NWT; tt /= NWT;
        const int dck = tt % NDC; tt /= NDC;
        const int b   = tt;
        const int h0  = ht * HT;
        const int wt0 = wt * WT;
        const int dc0 = dck * DC;
        const int pstart = dc0 - 4 > 0 ? dc0 - 4 : 0;
        const int pend   = dc0 + DC + 4 < DD ? dc0 + DC + 4 : DD;  // planes, excl
        const int plast  = dc0 + DC + 4;                            // rounds, incl

        const int wr  = tid >> 1, wseg = tid & 1;   // W role (tid < 48)
        const int hro = tid >> 2, hqd  = tid & 3;   // H role (tid < 64)
        const int ho  = tid >> 4, wo   = tid & 15;  // cc role (all 256)

        const float* pmb = mv + (size_t)b * VOL;
        const float* pfb = fx + (size_t)b * VOL;

        float s0 = 0.f, s1 = 0.f, s2 = 0.f, s3 = 0.f, s4 = 0.f, acc = 0.f;
        int scur = pstart % 9;
        const float inv_win = 1.0f / 729.0f;

        for (int p = pstart; p <= plast; ++p) {
            const int sprev = (scur == 0) ? 8 : scur - 1;

            // ---------------- stage A : cc bookkeeping (all threads) -------
            if (p > pstart && p <= pend) {          // add plane p-1
                s0 += (float)ring[sprev][0][ho][wo];
                s1 += (float)ring[sprev][1][ho][wo];
                s2 += (float)ring[sprev][2][ho][wo];
                s3 += (float)ring[sprev][3][ho][wo];
                s4 += (float)ring[sprev][4][ho][wo];
            }
            if (p >= dc0 + 5) {                     // emit center c = p-5
                float cross = fmaf(-(s0 * s1), inv_win, s4);
                float pv = fmaxf(fmaf(-(s0 * s0), inv_win, s2), 0.f);
                float tv = fmaxf(fmaf(-(s1 * s1), inv_win, s3), 0.f);
                float cc = cross * cross / (pv * tv + 0.001f);
                acc += fminf(fmaxf(cc, 0.f), 1.f);
            }
            if (p - 9 >= pstart) {                  // sub plane p-9 (slot scur)
                s0 -= (float)ring[scur][0][ho][wo];
                s1 -= (float)ring[scur][1][ho][wo];
                s2 -= (float)ring[scur][2][ho][wo];
                s3 -= (float)ring[scur][3][ho][wo];
                s4 -= (float)ring[scur][4][ho][wo];
            }

            // ---------------- stage A : W staging of plane p ---------------
            if (p < pend && tid < 48) {
                const int hr = h0 - 4 + wr;          // staged row
                const int a  = wt0 + wseg * 8 - 4;   // aligned f4 window start
                float vm[16], vf[16];
#pragma unroll
                for (int i = 0; i < 16; ++i) { vm[i] = 0.f; vf[i] = 0.f; }
                if ((unsigned)hr < (unsigned)HH) {
                    const float* rm = pmb + (size_t)p * PLANE + (size_t)hr * WW;
                    const float* rf = pfb + (size_t)p * PLANE + (size_t)hr * WW;
#pragma unroll
                    for (int j = 0; j < 4; ++j) {
                        const int w4 = a + 4 * j;
                        if (w4 >= 0 && w4 <= WW - 4) {
                            float4 m4 = *(const float4*)(rm + w4);
                            float4 f4 = *(const float4*)(rf + w4);
                            vm[4*j+0] = m4.x; vm[4*j+1] = m4.y;
                            vm[4*j+2] = m4.z; vm[4*j+3] = m4.w;
                            vf[4*j+0] = f4.x; vf[4*j+1] = f4.y;
                            vf[4*j+2] = f4.z; vf[4*j+3] = f4.w;
                        }
                    }
                }
                float o0[8], o1[8], o2[8], o3[8], o4[8];
                float sm = 0.f, sf = 0.f, smm = 0.f, sff = 0.f, smf = 0.f;
#pragma unroll
                for (int i = 0; i < 9; ++i) {
                    float m = vm[i], f = vf[i];
                    sm += m; sf += f;
                    smm = fmaf(m, m, smm);
                    sff = fmaf(f, f, sff);
                    smf = fmaf(m, f, smf);
                }
                o0[0] = sm; o1[0] = sf; o2[0] = smm; o3[0] = sff; o4[0] = smf;
#pragma unroll
                for (int k = 1; k < 8; ++k) {
                    float am = vm[k + 8], bm = vm[k - 1];
                    float af = vf[k + 8], bf = vf[k - 1];
                    sm  += am - bm;
                    sf  += af - bf;
                    smm += fmaf(am, am, -(bm * bm));
                    sff += fmaf(af, af, -(bf * bf));
                    smf += fmaf(am, af, -(bm * bf));
                    o0[k] = sm; o1[k] = sf; o2[k] = smm; o3[k] = sff; o4[k] = smf;
                }
                const int wc = wseg * 8;
                *(float4*)&ws[0][wr][wc]     = *(float4*)&o0[0];
                *(float4*)&ws[0][wr][wc + 4] = *(float4*)&o0[4];
                *(float4*)&ws[1][wr][wc]     = *(float4*)&o1[0];
                *(float4*)&ws[1][wr][wc + 4] = *(float4*)&o1[4];
                *(float4*)&ws[2][wr][wc]     = *(float4*)&o2[0];
                *(float4*)&ws[2][wr][wc + 4] = *(float4*)&o2[4];
                *(float4*)&ws[3][wr][wc]     = *(float4*)&o3[0];
                *(float4*)&ws[3][wr][wc + 4] = *(float4*)&o3[4];
                *(float4*)&ws[4][wr][wc]     = *(float4*)&o4[0];
                *(float4*)&ws[4][wr][wc + 4] = *(float4*)&o4[4];
            }
            if (p < pend) __syncthreads();

            // ---------------- stage B : H sums -> ring[scur] ---------------
            if (p < pend && tid < 64) {
#pragma unroll
                for (int f = 0; f < 5; ++f) {
                    float4 s = make_float4(0.f, 0.f, 0.f, 0.f);
#pragma unroll
                    for (int t9 = 0; t9 < 9; ++t9) {
                        float4 v = *(const float4*)&ws[f][hro + t9][hqd * 4];
                        s.x += v.x; s.y += v.y; s.z += v.z; s.w += v.w;
                    }
                    h4 t;
                    t.x = (_Float16)s.x; t.y = (_Float16)s.y;
                    t.z = (_Float16)s.z; t.w = (_Float16)s.w;
                    *(h4*)&ring[scur][f][hro][hqd * 4] = t;
                }
            }
            if (p < pend) __syncthreads();

            scur = (scur == 8) ? 0 : scur + 1;
        }

        // deterministic block reduction
        for (int o = 32; o > 0; o >>= 1) acc += __shfl_down(acc, o, 64);
        const int lane = tid & 63, wid = tid >> 6;
        if (lane == 0) red[wid] = acc;
        __syncthreads();
        if (tid == 0) pcc[bx] = red[0] + red[1] + red[2] + red[3];
        return;
    }

    // ---- grad: L1 forward diffs on flow, d-walking float4 chunks ----
    const int gid = (bx - NCCB) * 256 + tid;     // 0..307199
    const int w4  = gid % 40;
    int t = gid / 40;
    const int h  = t % HH;  t /= HH;
    const int dc = t % (DD / GCHD); t /= (DD / GCHD);
    const int bc = t;                            // 0..5
    const int d0 = dc * GCHD;
    const int w  = w4 * 4;

    const float* base = fl + (size_t)bc * VOL;
    float acc = 0.f;
    float4 v = *(const float4*)(base + ((size_t)d0 * HH + h) * WW + w);
    for (int d = d0; d < d0 + GCHD; ++d) {
        const float* pd = base + ((size_t)d * HH + h) * WW + w;
        float4 vn = v;
        if (d < DD - 1) {
            vn = *(const float4*)(pd + PLANE);
            acc += fabsf(vn.x - v.x) + fabsf(vn.y - v.y) +
                   fabsf(vn.z - v.z) + fabsf(vn.w - v.w);
        }
        if (h < HH - 1) {
            float4 vh = *(const float4*)(pd + WW);
            acc += fabsf(vh.x - v.x) + fabsf(vh.y - v.y) +
                   fabsf(vh.z - v.z) + fabsf(vh.w - v.w);
        }
        acc += fabsf(v.y - v.x) + fabsf(v.z - v.y) + fabsf(v.w - v.z);
        if (w < WW - 4) acc += fabsf(pd[4] - v.w);
        v = vn;
    }

    for (int o = 32; o > 0; o >>= 1) acc += __shfl_down(acc, o, 64);
    const int lane = tid & 63, wid = tid >> 6;
    if (lane == 0) red[wid] = acc;
    __syncthreads();
    if (tid == 0) pg[bx - NCCB] = red[0] + red[1] + red[2] + red[3];
}

// ---------------------------------------------------------------------------
// finalize: deterministic reduction of partials -> scalar loss
// ---------------------------------------------------------------------------
__global__ __launch_bounds__(256) void finalize(const float* __restrict__ pcc, int ncc,
                                                const float* __restrict__ pg, int ng,
                                                float* __restrict__ out) {
    __shared__ float red[4];
    int lane = threadIdx.x & 63, wid = threadIdx.x >> 6;

    float a = 0.f;
    for (int i = threadIdx.x; i < ncc; i += 256) a += pcc[i];
    for (int o = 32; o > 0; o >>= 1) a += __shfl_down(a, o, 64);
    if (lane == 0) red[wid] = a;
    __syncthreads();
    float asum = red[0] + red[1] + red[2] + red[3];
    __syncthreads();

    float g = 0.f;
    for (int i = threadIdx.x; i < ng; i += 256) g += pg[i];
    for (int o = 32; o > 0; o >>= 1) g += __shfl_down(g, o, 64);
    if (lane == 0) red[wid] = g;
    __syncthreads();
    float gsum = red[0] + red[1] + red[2] + red[3];

    if (threadIdx.x == 0) {
        float sim = 1.0f - asum / 8192000.0f;          // mean over (2,1,160,160,160)
        float reg = gsum / 73267200.0f;                // 3 * (2*3*159*160*160)
        out[0] = sim + reg;
    }
}

// ---------------------------------------------------------------------------
extern "C" void kernel_launch(void* const* d_in, const int* in_sizes, int n_in,
                              void* d_out, int out_size, void* d_ws, size_t ws_size,
                              hipStream_t stream) {
    const float* moved  = (const float*)d_in[0];
    const float* fixedp = (const float*)d_in[1];
    const float* flow   = (const float*)d_in[2];
    float* out = (float*)d_out;

    float* pcc = (float*)d_ws;           // NCCB floats
    float* pg  = pcc + NCCB;             // GBLK floats

    fused<<<NCCB + GBLK, 256, 0, stream>>>(moved, fixedp, flow, pcc, pg);
    finalize<<<1, 256, 0, stream>>>(pcc, NCCB, pg, GBLK, out);
}

// Round 12
// 118.910 us; speedup vs baseline: 1.1400x; 1.0991x over previous
//
#include <hip/hip_runtime.h>

#define DD 160
#define HH 160
#define WW 160
#define VOL (DD * HH * WW)   // per-batch volume = 4,096,000
#define PLANE (HH * WW)      // 25,600
#define NB 2

// pass 1: D-sum streaming (4 columns/thread, add/sub window, burst writes)
#define DCH 20               // d-centers per block
#define NDSP (DD / DCH)      // 8
#define DSBLK (PLANE / 1024) // 25 quad-tiles (256 thr * 4 cols)
#define NDSUM (DSBLK * NDSP * NB)  // 400 blocks
#define BG 5                 // buffered planes per write burst (20 = 4 bursts)

// pass 2: WH + cc
#define HT 16
#define HS (HT + 8)          // 24 staged rows
#define LDWH 168             // LDS row stride (halves), 336B
#define WHBLK ((HH / HT) * DD * NB)   // 3200

// pass 3: grad
#define GCHD 20
#define GBLK (NB * 3 * (DD / GCHD) * HH * (WW / 4) / 256)   // 1200 blocks

typedef _Float16 h8 __attribute__((ext_vector_type(8)));
typedef _Float16 h4 __attribute__((ext_vector_type(4)));

// ---------------------------------------------------------------------------
// Pass 1: D-direction box sums of the 5 moment fields (SoA fp16 output).
// Add/sub sliding window on raw m,f. READ/WRITE PHASE SEPARATION: 5 planes of
// packed h4 outputs buffered in registers (unrolled, compile-time indices),
// then a 25-store pure write burst. Grid: 400 blocks.
// ---------------------------------------------------------------------------
__global__ __launch_bounds__(256) void dsum(const float* __restrict__ mv,
                                            const float* __restrict__ fx,
                                            _Float16* __restrict__ fields) {
    const int bx  = blockIdx.x;
    const int tid = threadIdx.x;

    const int qt  = bx % DSBLK;          // quad-tile
    const int rem = bx / DSBLK;
    const int dsp = rem % NDSP;
    const int b   = rem / NDSP;
    const int hw  = (qt * 256 + tid) * 4;   // 0..25596
    const int c0  = dsp * DCH;
    const int cend = c0 + DCH;

    const float* pm = mv + (size_t)b * VOL + hw;
    const float* pf = fx + (size_t)b * VOL + hw;
    _Float16*    fb = fields + (size_t)b * 5 * VOL + hw;

    float4 s0 = {0,0,0,0}, s1 = {0,0,0,0}, s2 = {0,0,0,0},
           s3 = {0,0,0,0}, s4 = {0,0,0,0};

#define ACC4(m4, f4, sgn)                                              \
    s0.x sgn m4.x; s0.y sgn m4.y; s0.z sgn m4.z; s0.w sgn m4.w;        \
    s1.x sgn f4.x; s1.y sgn f4.y; s1.z sgn f4.z; s1.w sgn f4.w;        \
    s2.x sgn m4.x * m4.x; s2.y sgn m4.y * m4.y;                        \
    s2.z sgn m4.z * m4.z; s2.w sgn m4.w * m4.w;                        \
    s3.x sgn f4.x * f4.x; s3.y sgn f4.y * f4.y;                        \
    s3.z sgn f4.z * f4.z; s3.w sgn f4.w * f4.w;                        \
    s4.x sgn m4.x * f4.x; s4.y sgn m4.y * f4.y;                        \
    s4.z sgn m4.z * f4.z; s4.w sgn m4.w * f4.w;

    {   // warm-up: planes [c0-4, c0+4] clipped
        int lo = c0 - 4 > 0 ? c0 - 4 : 0;
        int hi = c0 + 4 < DD - 1 ? c0 + 4 : DD - 1;
        for (int dd = lo; dd <= hi; ++dd) {
            float4 m4 = *(const float4*)(pm + (size_t)dd * PLANE);
            float4 f4 = *(const float4*)(pf + (size_t)dd * PLANE);
            ACC4(m4, f4, +=)
        }
    }

#pragma unroll
    for (int g = 0; g < DCH / BG; ++g) {
        h4 buf[BG][5];
        // ---- read + math phase (pure reads) ----
#pragma unroll
        for (int k = 0; k < BG; ++k) {
            const int d = c0 + g * BG + k;
            buf[k][0].x = (_Float16)s0.x; buf[k][0].y = (_Float16)s0.y;
            buf[k][0].z = (_Float16)s0.z; buf[k][0].w = (_Float16)s0.w;
            buf[k][1].x = (_Float16)s1.x; buf[k][1].y = (_Float16)s1.y;
            buf[k][1].z = (_Float16)s1.z; buf[k][1].w = (_Float16)s1.w;
            buf[k][2].x = (_Float16)s2.x; buf[k][2].y = (_Float16)s2.y;
            buf[k][2].z = (_Float16)s2.z; buf[k][2].w = (_Float16)s2.w;
            buf[k][3].x = (_Float16)s3.x; buf[k][3].y = (_Float16)s3.y;
            buf[k][3].z = (_Float16)s3.z; buf[k][3].w = (_Float16)s3.w;
            buf[k][4].x = (_Float16)s4.x; buf[k][4].y = (_Float16)s4.y;
            buf[k][4].z = (_Float16)s4.z; buf[k][4].w = (_Float16)s4.w;

            if (d + 1 < cend) {
                if (d + 5 < DD) {
                    float4 m4 = *(const float4*)(pm + (size_t)(d + 5) * PLANE);
                    float4 f4 = *(const float4*)(pf + (size_t)(d + 5) * PLANE);
                    ACC4(m4, f4, +=)
                }
                if (d - 4 >= 0) {
                    float4 m4 = *(const float4*)(pm + (size_t)(d - 4) * PLANE);
                    float4 f4 = *(const float4*)(pf + (size_t)(d - 4) * PLANE);
                    ACC4(m4, f4, -=)
                }
            }
        }
        // ---- write burst phase (pure writes, 25 stores) ----
#pragma unroll
        for (int f = 0; f < 5; ++f) {
#pragma unroll
            for (int k = 0; k < BG; ++k) {
                const int d = c0 + g * BG + k;
                *(h4*)(fb + (size_t)f * VOL + (size_t)d * PLANE) = buf[k][f];
            }
        }
    }
#undef ACC4
}

// ---------------------------------------------------------------------------
// Pass 2: W+H box sums of the 5 D-summed fields + per-voxel cc + reduction.
// Read-only on fields (SoA). Block: 512 thr, tile 16h x 160w at one (d, b).
// ---------------------------------------------------------------------------
__global__ __launch_bounds__(512, 6) void ncc_whcc(const _Float16* __restrict__ fields,
                                                   float* __restrict__ partial) {
    __shared__ _Float16 ws[5][HS][LDWH];
    __shared__ float red[8];

    const int hx  = blockIdx.x;        // 0..9
    const int d   = blockIdx.y;        // 0..159
    const int b   = blockIdx.z;        // 0..1
    const int h0  = hx * HT;
    const int tid = threadIdx.x;

    if (tid < 480) {
        const int r  = tid / 20;       // 0..23 staged row
        const int s  = tid - r * 20;   // 0..19 octet
        const int h  = h0 - 4 + r;
        const int w0 = 8 * s;
        const bool rowok = (unsigned)h < (unsigned)HH;

#pragma unroll
        for (int f = 0; f < 5; ++f) {
            float v[16];
#pragma unroll
            for (int i = 0; i < 16; ++i) v[i] = 0.f;
            if (rowok) {
                const _Float16* fr = fields + (size_t)(b * 5 + f) * VOL
                                            + ((size_t)d * HH + h) * WW;
                if (s > 0) {
                    h4 a = *(const h4*)(fr + w0 - 4);
                    v[0] = (float)a.x; v[1] = (float)a.y; v[2] = (float)a.z; v[3] = (float)a.w;
                }
                h4 a1 = *(const h4*)(fr + w0);
                v[4] = (float)a1.x; v[5] = (float)a1.y; v[6] = (float)a1.z; v[7] = (float)a1.w;
                h4 a2 = *(const h4*)(fr + w0 + 4);
                v[8] = (float)a2.x; v[9] = (float)a2.y; v[10] = (float)a2.z; v[11] = (float)a2.w;
                if (s < 19) {
                    h4 a3 = *(const h4*)(fr + w0 + 8);
                    v[12] = (float)a3.x; v[13] = (float)a3.y; v[14] = (float)a3.z; v[15] = (float)a3.w;
                }
            }
            float o[8];
            float sum = 0.f;
#pragma unroll
            for (int i = 0; i < 9; ++i) sum += v[i];
            o[0] = sum;
#pragma unroll
            for (int k = 1; k < 8; ++k) {
                sum += v[k + 8] - v[k - 1];
                o[k] = sum;
            }
            h8 pk;
#pragma unroll
            for (int j = 0; j < 8; ++j) pk[j] = (_Float16)o[j];
            *(h8*)&ws[f][r][w0] = pk;
        }
    }
    __syncthreads();

    float acc = 0.f;
    if (tid < 320) {
        const int ro  = tid / 20;      // 0..15 output row
        const int oct = tid - ro * 20; // 0..19
        const int w   = 8 * oct;

        float s0[8], s1[8], s2[8], s3[8], s4[8];
#pragma unroll
        for (int j = 0; j < 8; ++j) { s0[j]=0.f; s1[j]=0.f; s2[j]=0.f; s3[j]=0.f; s4[j]=0.f; }
#pragma unroll
        for (int t = 0; t < 9; ++t) {
            h8 v0 = *(const h8*)&ws[0][ro + t][w];
            h8 v1 = *(const h8*)&ws[1][ro + t][w];
            h8 v2 = *(const h8*)&ws[2][ro + t][w];
            h8 v3 = *(const h8*)&ws[3][ro + t][w];
            h8 v4 = *(const h8*)&ws[4][ro + t][w];
#pragma unroll
            for (int j = 0; j < 8; ++j) {
                s0[j] += (float)v0[j]; s1[j] += (float)v1[j];
                s2[j] += (float)v2[j]; s3[j] += (float)v3[j];
                s4[j] += (float)v4[j];
            }
        }
        const float inv_win = 1.0f / 729.0f;
#pragma unroll
        for (int j = 0; j < 8; ++j) {
            float cross = fmaf(-(s0[j] * s1[j]), inv_win, s4[j]);
            float pv = fmaxf(fmaf(-(s0[j] * s0[j]), inv_win, s2[j]), 0.f);
            float tv = fmaxf(fmaf(-(s1[j] * s1[j]), inv_win, s3[j]), 0.f);
            float cc = cross * cross / (pv * tv + 0.001f);
            acc += fminf(fmaxf(cc, 0.f), 1.f);
        }
    }

    for (int o = 32; o > 0; o >>= 1) acc += __shfl_down(acc, o, 64);
    int lane = tid & 63, wid = tid >> 6;
    if (lane == 0) red[wid] = acc;
    __syncthreads();
    if (tid == 0) {
        float r8 = 0.f;
#pragma unroll
        for (int i = 0; i < 8; ++i) r8 += red[i];
        partial[((size_t)b * DD + d) * (HH / HT) + hx] = r8;
    }
}

// ---------------------------------------------------------------------------
// Pass 3: L1 gradient penalty — d-walking float4 chunks (own small kernel).
// ---------------------------------------------------------------------------
__global__ __launch_bounds__(256) void grad_red(const float* __restrict__ fl,
                                                float* __restrict__ partial) {
    const int gid = blockIdx.x * 256 + threadIdx.x;  // 0..307199
    const int w4  = gid % 40;
    int t = gid / 40;
    const int h  = t % HH;  t /= HH;
    const int dc = t % (DD / GCHD); t /= (DD / GCHD);
    const int bc = t;                                // 0..5
    const int d0 = dc * GCHD;
    const int w  = w4 * 4;

    const float* base = fl + (size_t)bc * VOL;
    float acc = 0.f;
    float4 v = *(const float4*)(base + ((size_t)d0 * HH + h) * WW + w);
    for (int d = d0; d < d0 + GCHD; ++d) {
        const float* pd = base + ((size_t)d * HH + h) * WW + w;
        float4 vn = v;
        if (d < DD - 1) {
            vn = *(const float4*)(pd + PLANE);
            acc += fabsf(vn.x - v.x) + fabsf(vn.y - v.y) +
                   fabsf(vn.z - v.z) + fabsf(vn.w - v.w);
        }
        if (h < HH - 1) {
            float4 vh = *(const float4*)(pd + WW);
            acc += fabsf(vh.x - v.x) + fabsf(vh.y - v.y) +
                   fabsf(vh.z - v.z) + fabsf(vh.w - v.w);
        }
        acc += fabsf(v.y - v.x) + fabsf(v.z - v.y) + fabsf(v.w - v.z);
        if (w < WW - 4) acc += fabsf(pd[4] - v.w);
        v = vn;
    }

    for (int o = 32; o > 0; o >>= 1) acc += __shfl_down(acc, o, 64);
    __shared__ float red[4];
    int lane = threadIdx.x & 63, wid = threadIdx.x >> 6;
    if (lane == 0) red[wid] = acc;
    __syncthreads();
    if (threadIdx.x == 0) partial[blockIdx.x] = red[0] + red[1] + red[2] + red[3];
}

// ---------------------------------------------------------------------------
// finalize: deterministic reduction of partials -> scalar loss
// ---------------------------------------------------------------------------
__global__ __launch_bounds__(256) void finalize(const float* __restrict__ pcc, int ncc,
                                                const float* __restrict__ pg, int ng,
                                                float* __restrict__ out) {
    __shared__ float red[4];
    int lane = threadIdx.x & 63, wid = threadIdx.x >> 6;

    float a = 0.f;
    for (int i = threadIdx.x; i < ncc; i += 256) a += pcc[i];
    for (int o = 32; o > 0; o >>= 1) a += __shfl_down(a, o, 64);
    if (lane == 0) red[wid] = a;
    __syncthreads();
    float asum = red[0] + red[1] + red[2] + red[3];
    __syncthreads();

    float g = 0.f;
    for (int i = threadIdx.x; i < ng; i += 256) g += pg[i];
    for (int o = 32; o > 0; o >>= 1) g += __shfl_down(g, o, 64);
    if (lane == 0) red[wid] = g;
    __syncthreads();
    float gsum = red[0] + red[1] + red[2] + red[3];

    if (threadIdx.x == 0) {
        float sim = 1.0f - asum / 8192000.0f;          // mean over (2,1,160,160,160)
        float reg = gsum / 73267200.0f;                // 3 * (2*3*159*160*160)
        out[0] = sim + reg;
    }
}

// ---------------------------------------------------------------------------
extern "C" void kernel_launch(void* const* d_in, const int* in_sizes, int n_in,
                              void* d_out, int out_size, void* d_ws, size_t ws_size,
                              hipStream_t stream) {
    const float* moved  = (const float*)d_in[0];
    const float* fixedp = (const float*)d_in[1];
    const float* flow   = (const float*)d_in[2];
    float* out = (float*)d_out;

    _Float16* fields = (_Float16*)d_ws;                   // NB*5*VOL fp16 SoA (81.9 MB)
    float* pcc = (float*)(fields + (size_t)NB * 5 * VOL); // WHBLK floats
    float* pg  = pcc + WHBLK;                             // GBLK floats

    dsum<<<NDSUM, 256, 0, stream>>>(moved, fixedp, fields);
    ncc_whcc<<<dim3(HH / HT, DD, NB), 512, 0, stream>>>(fields, pcc);
    grad_red<<<GBLK, 256, 0, stream>>>(flow, pg);
    finalize<<<1, 256, 0, stream>>>(pcc, WHBLK, pg, GBLK, out);
}

// Round 13
// 116.501 us; speedup vs baseline: 1.1635x; 1.0207x over previous
//
#include <hip/hip_runtime.h>

#define DD 160
#define HH 160
#define WW 160
#define VOL (DD * HH * WW)   // per-batch volume = 4,096,000
#define PLANE (HH * WW)      // 25,600
#define NB 2

// pass 1: D-sum streaming (4 columns/thread, add/sub window, burst writes)
#define DCH 10               // d-centers per block
#define NDSP (DD / DCH)      // 16
#define DSBLK (PLANE / 1024) // 25 quad-tiles (256 thr * 4 cols)
#define NDSUM (DSBLK * NDSP * NB)  // 800 blocks
#define BG 5                 // buffered planes per write burst

// pass 2: WH + cc
#define HT 16
#define HS (HT + 8)          // 24 staged rows
#define LDWH 168             // LDS row stride (halves), 336B
#define WHBLK ((HH / HT) * DD * NB)   // 3200

// pass 3: grad
#define GCHD 20
#define GBLK (NB * 3 * (DD / GCHD) * HH * (WW / 4) / 256)   // 1200 blocks

typedef _Float16 h8 __attribute__((ext_vector_type(8)));
typedef _Float16 h4 __attribute__((ext_vector_type(4)));

// ---------------------------------------------------------------------------
// Pass 1: D-direction box sums of the 5 moment fields (SoA fp16 output).
// Add/sub sliding window on raw m,f; register-buffered write bursts
// (read phase / write phase separation). Grid: 800 blocks.
// ---------------------------------------------------------------------------
__global__ __launch_bounds__(256) void dsum(const float* __restrict__ mv,
                                            const float* __restrict__ fx,
                                            _Float16* __restrict__ fields) {
    const int bx  = blockIdx.x;
    const int tid = threadIdx.x;

    const int qt  = bx % DSBLK;          // quad-tile
    const int rem = bx / DSBLK;
    const int dsp = rem % NDSP;
    const int b   = rem / NDSP;
    const int hw  = (qt * 256 + tid) * 4;   // 0..25596
    const int c0  = dsp * DCH;
    const int cend = c0 + DCH;

    const float* pm = mv + (size_t)b * VOL + hw;
    const float* pf = fx + (size_t)b * VOL + hw;
    _Float16*    fb = fields + (size_t)b * 5 * VOL + hw;

    float4 s0 = {0,0,0,0}, s1 = {0,0,0,0}, s2 = {0,0,0,0},
           s3 = {0,0,0,0}, s4 = {0,0,0,0};

#define ACC4(m4, f4, sgn)                                              \
    s0.x sgn m4.x; s0.y sgn m4.y; s0.z sgn m4.z; s0.w sgn m4.w;        \
    s1.x sgn f4.x; s1.y sgn f4.y; s1.z sgn f4.z; s1.w sgn f4.w;        \
    s2.x sgn m4.x * m4.x; s2.y sgn m4.y * m4.y;                        \
    s2.z sgn m4.z * m4.z; s2.w sgn m4.w * m4.w;                        \
    s3.x sgn f4.x * f4.x; s3.y sgn f4.y * f4.y;                        \
    s3.z sgn f4.z * f4.z; s3.w sgn f4.w * f4.w;                        \
    s4.x sgn m4.x * f4.x; s4.y sgn m4.y * f4.y;                        \
    s4.z sgn m4.z * f4.z; s4.w sgn m4.w * f4.w;

    {   // warm-up: planes [c0-4, c0+4] clipped
        int lo = c0 - 4 > 0 ? c0 - 4 : 0;
        int hi = c0 + 4 < DD - 1 ? c0 + 4 : DD - 1;
        for (int dd = lo; dd <= hi; ++dd) {
            float4 m4 = *(const float4*)(pm + (size_t)dd * PLANE);
            float4 f4 = *(const float4*)(pf + (size_t)dd * PLANE);
            ACC4(m4, f4, +=)
        }
    }

#pragma unroll
    for (int g = 0; g < DCH / BG; ++g) {
        h4 buf[BG][5];
        // ---- read + math phase (pure reads) ----
#pragma unroll
        for (int k = 0; k < BG; ++k) {
            const int d = c0 + g * BG + k;
            buf[k][0].x = (_Float16)s0.x; buf[k][0].y = (_Float16)s0.y;
            buf[k][0].z = (_Float16)s0.z; buf[k][0].w = (_Float16)s0.w;
            buf[k][1].x = (_Float16)s1.x; buf[k][1].y = (_Float16)s1.y;
            buf[k][1].z = (_Float16)s1.z; buf[k][1].w = (_Float16)s1.w;
            buf[k][2].x = (_Float16)s2.x; buf[k][2].y = (_Float16)s2.y;
            buf[k][2].z = (_Float16)s2.z; buf[k][2].w = (_Float16)s2.w;
            buf[k][3].x = (_Float16)s3.x; buf[k][3].y = (_Float16)s3.y;
            buf[k][3].z = (_Float16)s3.z; buf[k][3].w = (_Float16)s3.w;
            buf[k][4].x = (_Float16)s4.x; buf[k][4].y = (_Float16)s4.y;
            buf[k][4].z = (_Float16)s4.z; buf[k][4].w = (_Float16)s4.w;

            if (d + 1 < cend) {
                if (d + 5 < DD) {
                    float4 m4 = *(const float4*)(pm + (size_t)(d + 5) * PLANE);
                    float4 f4 = *(const float4*)(pf + (size_t)(d + 5) * PLANE);
                    ACC4(m4, f4, +=)
                }
                if (d - 4 >= 0) {
                    float4 m4 = *(const float4*)(pm + (size_t)(d - 4) * PLANE);
                    float4 f4 = *(const float4*)(pf + (size_t)(d - 4) * PLANE);
                    ACC4(m4, f4, -=)
                }
            }
        }
        // ---- write burst phase (pure writes, 25 stores) ----
#pragma unroll
        for (int f = 0; f < 5; ++f) {
#pragma unroll
            for (int k = 0; k < BG; ++k) {
                const int d = c0 + g * BG + k;
                *(h4*)(fb + (size_t)f * VOL + (size_t)d * PLANE) = buf[k][f];
            }
        }
    }
#undef ACC4
}

// ---------------------------------------------------------------------------
// Pass 2: W+H box sums of the 5 D-summed fields + per-voxel cc + reduction.
// Stage B accumulates the 9-tap H-sum in PACKED fp16 (v_pk_add_f16) —
// converts to f32 only for the final cc math. Block: 512 thr. Grid (10,160,2).
// ---------------------------------------------------------------------------
__global__ __launch_bounds__(512, 6) void ncc_whcc(const _Float16* __restrict__ fields,
                                                   float* __restrict__ partial) {
    __shared__ _Float16 ws[5][HS][LDWH];
    __shared__ float red[8];

    const int hx  = blockIdx.x;        // 0..9
    const int d   = blockIdx.y;        // 0..159
    const int b   = blockIdx.z;        // 0..1
    const int h0  = hx * HT;
    const int tid = threadIdx.x;

    if (tid < 480) {
        const int r  = tid / 20;       // 0..23 staged row
        const int s  = tid - r * 20;   // 0..19 octet
        const int h  = h0 - 4 + r;
        const int w0 = 8 * s;
        const bool rowok = (unsigned)h < (unsigned)HH;

#pragma unroll
        for (int f = 0; f < 5; ++f) {
            float v[16];
#pragma unroll
            for (int i = 0; i < 16; ++i) v[i] = 0.f;
            if (rowok) {
                const _Float16* fr = fields + (size_t)(b * 5 + f) * VOL
                                            + ((size_t)d * HH + h) * WW;
                if (s > 0) {
                    h4 a = *(const h4*)(fr + w0 - 4);
                    v[0] = (float)a.x; v[1] = (float)a.y; v[2] = (float)a.z; v[3] = (float)a.w;
                }
                h4 a1 = *(const h4*)(fr + w0);
                v[4] = (float)a1.x; v[5] = (float)a1.y; v[6] = (float)a1.z; v[7] = (float)a1.w;
                h4 a2 = *(const h4*)(fr + w0 + 4);
                v[8] = (float)a2.x; v[9] = (float)a2.y; v[10] = (float)a2.z; v[11] = (float)a2.w;
                if (s < 19) {
                    h4 a3 = *(const h4*)(fr + w0 + 8);
                    v[12] = (float)a3.x; v[13] = (float)a3.y; v[14] = (float)a3.z; v[15] = (float)a3.w;
                }
            }
            float o[8];
            float sum = 0.f;
#pragma unroll
            for (int i = 0; i < 9; ++i) sum += v[i];
            o[0] = sum;
#pragma unroll
            for (int k = 1; k < 8; ++k) {
                sum += v[k + 8] - v[k - 1];
                o[k] = sum;
            }
            h8 pk;
#pragma unroll
            for (int j = 0; j < 8; ++j) pk[j] = (_Float16)o[j];
            *(h8*)&ws[f][r][w0] = pk;
        }
    }
    __syncthreads();

    float acc = 0.f;
    if (tid < 320) {
        const int ro  = tid / 20;      // 0..15 output row
        const int oct = tid - ro * 20; // 0..19
        const int w   = 8 * oct;

        // packed fp16 9-tap column sums (v_pk_add_f16)
        h8 a0 = *(const h8*)&ws[0][ro][w];
        h8 a1 = *(const h8*)&ws[1][ro][w];
        h8 a2 = *(const h8*)&ws[2][ro][w];
        h8 a3 = *(const h8*)&ws[3][ro][w];
        h8 a4 = *(const h8*)&ws[4][ro][w];
#pragma unroll
        for (int t = 1; t < 9; ++t) {
            a0 += *(const h8*)&ws[0][ro + t][w];
            a1 += *(const h8*)&ws[1][ro + t][w];
            a2 += *(const h8*)&ws[2][ro + t][w];
            a3 += *(const h8*)&ws[3][ro + t][w];
            a4 += *(const h8*)&ws[4][ro + t][w];
        }
        const float inv_win = 1.0f / 729.0f;
#pragma unroll
        for (int j = 0; j < 8; ++j) {
            float s0 = (float)a0[j], s1 = (float)a1[j];
            float s2 = (float)a2[j], s3 = (float)a3[j], s4 = (float)a4[j];
            float cross = fmaf(-(s0 * s1), inv_win, s4);
            float pv = fmaxf(fmaf(-(s0 * s0), inv_win, s2), 0.f);
            float tv = fmaxf(fmaf(-(s1 * s1), inv_win, s3), 0.f);
            float cc = cross * cross / (pv * tv + 0.001f);
            acc += fminf(fmaxf(cc, 0.f), 1.f);
        }
    }

    for (int o = 32; o > 0; o >>= 1) acc += __shfl_down(acc, o, 64);
    int lane = tid & 63, wid = tid >> 6;
    if (lane == 0) red[wid] = acc;
    __syncthreads();
    if (tid == 0) {
        float r8 = 0.f;
#pragma unroll
        for (int i = 0; i < 8; ++i) r8 += red[i];
        partial[((size_t)b * DD + d) * (HH / HT) + hx] = r8;
    }
}

// ---------------------------------------------------------------------------
// Pass 3: L1 gradient penalty — d-walking float4 chunks.
// ---------------------------------------------------------------------------
__global__ __launch_bounds__(256) void grad_red(const float* __restrict__ fl,
                                                float* __restrict__ partial) {
    const int gid = blockIdx.x * 256 + threadIdx.x;  // 0..307199
    const int w4  = gid % 40;
    int t = gid / 40;
    const int h  = t % HH;  t /= HH;
    const int dc = t % (DD / GCHD); t /= (DD / GCHD);
    const int bc = t;                                // 0..5
    const int d0 = dc * GCHD;
    const int w  = w4 * 4;

    const float* base = fl + (size_t)bc * VOL;
    float acc = 0.f;
    float4 v = *(const float4*)(base + ((size_t)d0 * HH + h) * WW + w);
    for (int d = d0; d < d0 + GCHD; ++d) {
        const float* pd = base + ((size_t)d * HH + h) * WW + w;
        float4 vn = v;
        if (d < DD - 1) {
            vn = *(const float4*)(pd + PLANE);
            acc += fabsf(vn.x - v.x) + fabsf(vn.y - v.y) +
                   fabsf(vn.z - v.z) + fabsf(vn.w - v.w);
        }
        if (h < HH - 1) {
            float4 vh = *(const float4*)(pd + WW);
            acc += fabsf(vh.x - v.x) + fabsf(vh.y - v.y) +
                   fabsf(vh.z - v.z) + fabsf(vh.w - v.w);
        }
        acc += fabsf(v.y - v.x) + fabsf(v.z - v.y) + fabsf(v.w - v.z);
        if (w < WW - 4) acc += fabsf(pd[4] - v.w);
        v = vn;
    }

    for (int o = 32; o > 0; o >>= 1) acc += __shfl_down(acc, o, 64);
    __shared__ float red[4];
    int lane = threadIdx.x & 63, wid = threadIdx.x >> 6;
    if (lane == 0) red[wid] = acc;
    __syncthreads();
    if (threadIdx.x == 0) partial[blockIdx.x] = red[0] + red[1] + red[2] + red[3];
}

// ---------------------------------------------------------------------------
// finalize: deterministic reduction of partials -> scalar loss
// ---------------------------------------------------------------------------
__global__ __launch_bounds__(256) void finalize(const float* __restrict__ pcc, int ncc,
                                                const float* __restrict__ pg, int ng,
                                                float* __restrict__ out) {
    __shared__ float red[4];
    int lane = threadIdx.x & 63, wid = threadIdx.x >> 6;

    float a = 0.f;
    for (int i = threadIdx.x; i < ncc; i += 256) a += pcc[i];
    for (int o = 32; o > 0; o >>= 1) a += __shfl_down(a, o, 64);
    if (lane == 0) red[wid] = a;
    __syncthreads();
    float asum = red[0] + red[1] + red[2] + red[3];
    __syncthreads();

    float g = 0.f;
    for (int i = threadIdx.x; i < ng; i += 256) g += pg[i];
    for (int o = 32; o > 0; o >>= 1) g += __shfl_down(g, o, 64);
    if (lane == 0) red[wid] = g;
    __syncthreads();
    float gsum = red[0] + red[1] + red[2] + red[3];

    if (threadIdx.x == 0) {
        float sim = 1.0f - asum / 8192000.0f;          // mean over (2,1,160,160,160)
        float reg = gsum / 73267200.0f;                // 3 * (2*3*159*160*160)
        out[0] = sim + reg;
    }
}

// ---------------------------------------------------------------------------
extern "C" void kernel_launch(void* const* d_in, const int* in_sizes, int n_in,
                              void* d_out, int out_size, void* d_ws, size_t ws_size,
                              hipStream_t stream) {
    const float* moved  = (const float*)d_in[0];
    const float* fixedp = (const float*)d_in[1];
    const float* flow   = (const float*)d_in[2];
    float* out = (float*)d_out;

    _Float16* fields = (_Float16*)d_ws;                   // NB*5*VOL fp16 SoA (81.9 MB)
    float* pcc = (float*)(fields + (size_t)NB * 5 * VOL); // WHBLK floats
    float* pg  = pcc + WHBLK;                             // GBLK floats

    dsum<<<NDSUM, 256, 0, stream>>>(moved, fixedp, fields);
    ncc_whcc<<<dim3(HH / HT, DD, NB), 512, 0, stream>>>(fields, pcc);
    grad_red<<<GBLK, 256, 0, stream>>>(flow, pg);
    finalize<<<1, 256, 0, stream>>>(pcc, WHBLK, pg, GBLK, out);
}

// Round 14
// 104.778 us; speedup vs baseline: 1.2937x; 1.1119x over previous
//
#include <hip/hip_runtime.h>

#define DD 160
#define HH 160
#define WW 160
#define VOL (DD * HH * WW)   // per-batch volume = 4,096,000
#define PLANE (HH * WW)      // 25,600
#define NB 2

// pass 1: D-sum streaming (4 columns/thread, add/sub window, burst writes)
#define DCH 20               // d-centers per block  (20 proven best: r12=35us, r13 DCH10=61us)
#define NDSP (DD / DCH)      // 8
#define DSBLK (PLANE / 1024) // 25 quad-tiles (256 thr * 4 cols)
#define NDSUM (DSBLK * NDSP * NB)  // 400 blocks
#define BG 5                 // buffered planes per write burst

// pass 2: WH + cc
#define HT 16
#define HS (HT + 8)          // 24 staged rows
#define LDWH 168             // LDS row stride (halves), 336B
#define WHBLK ((HH / HT) * DD * NB)   // 3200

// pass 3: grad
#define GCHD 20
#define GBLK (NB * 3 * (DD / GCHD) * HH * (WW / 4) / 256)   // 1200 blocks

typedef _Float16 h8 __attribute__((ext_vector_type(8)));
typedef _Float16 h4 __attribute__((ext_vector_type(4)));

// ---------------------------------------------------------------------------
// Pass 1: D-direction box sums of the 5 moment fields (SoA fp16 output).
// Add/sub sliding window on raw m,f; register-buffered write bursts
// (read phase / write phase separation). Grid: 400 blocks.
// ---------------------------------------------------------------------------
__global__ __launch_bounds__(256) void dsum(const float* __restrict__ mv,
                                            const float* __restrict__ fx,
                                            _Float16* __restrict__ fields) {
    const int bx  = blockIdx.x;
    const int tid = threadIdx.x;

    const int qt  = bx % DSBLK;          // quad-tile
    const int rem = bx / DSBLK;
    const int dsp = rem % NDSP;
    const int b   = rem / NDSP;
    const int hw  = (qt * 256 + tid) * 4;   // 0..25596
    const int c0  = dsp * DCH;
    const int cend = c0 + DCH;

    const float* pm = mv + (size_t)b * VOL + hw;
    const float* pf = fx + (size_t)b * VOL + hw;
    _Float16*    fb = fields + (size_t)b * 5 * VOL + hw;

    float4 s0 = {0,0,0,0}, s1 = {0,0,0,0}, s2 = {0,0,0,0},
           s3 = {0,0,0,0}, s4 = {0,0,0,0};

#define ACC4(m4, f4, sgn)                                              \
    s0.x sgn m4.x; s0.y sgn m4.y; s0.z sgn m4.z; s0.w sgn m4.w;        \
    s1.x sgn f4.x; s1.y sgn f4.y; s1.z sgn f4.z; s1.w sgn f4.w;        \
    s2.x sgn m4.x * m4.x; s2.y sgn m4.y * m4.y;                        \
    s2.z sgn m4.z * m4.z; s2.w sgn m4.w * m4.w;                        \
    s3.x sgn f4.x * f4.x; s3.y sgn f4.y * f4.y;                        \
    s3.z sgn f4.z * f4.z; s3.w sgn f4.w * f4.w;                        \
    s4.x sgn m4.x * f4.x; s4.y sgn m4.y * f4.y;                        \
    s4.z sgn m4.z * f4.z; s4.w sgn m4.w * f4.w;

    {   // warm-up: planes [c0-4, c0+4] clipped
        int lo = c0 - 4 > 0 ? c0 - 4 : 0;
        int hi = c0 + 4 < DD - 1 ? c0 + 4 : DD - 1;
        for (int dd = lo; dd <= hi; ++dd) {
            float4 m4 = *(const float4*)(pm + (size_t)dd * PLANE);
            float4 f4 = *(const float4*)(pf + (size_t)dd * PLANE);
            ACC4(m4, f4, +=)
        }
    }

#pragma unroll
    for (int g = 0; g < DCH / BG; ++g) {
        h4 buf[BG][5];
        // ---- read + math phase (pure reads) ----
#pragma unroll
        for (int k = 0; k < BG; ++k) {
            const int d = c0 + g * BG + k;
            buf[k][0].x = (_Float16)s0.x; buf[k][0].y = (_Float16)s0.y;
            buf[k][0].z = (_Float16)s0.z; buf[k][0].w = (_Float16)s0.w;
            buf[k][1].x = (_Float16)s1.x; buf[k][1].y = (_Float16)s1.y;
            buf[k][1].z = (_Float16)s1.z; buf[k][1].w = (_Float16)s1.w;
            buf[k][2].x = (_Float16)s2.x; buf[k][2].y = (_Float16)s2.y;
            buf[k][2].z = (_Float16)s2.z; buf[k][2].w = (_Float16)s2.w;
            buf[k][3].x = (_Float16)s3.x; buf[k][3].y = (_Float16)s3.y;
            buf[k][3].z = (_Float16)s3.z; buf[k][3].w = (_Float16)s3.w;
            buf[k][4].x = (_Float16)s4.x; buf[k][4].y = (_Float16)s4.y;
            buf[k][4].z = (_Float16)s4.z; buf[k][4].w = (_Float16)s4.w;

            if (d + 1 < cend) {
                if (d + 5 < DD) {
                    float4 m4 = *(const float4*)(pm + (size_t)(d + 5) * PLANE);
                    float4 f4 = *(const float4*)(pf + (size_t)(d + 5) * PLANE);
                    ACC4(m4, f4, +=)
                }
                if (d - 4 >= 0) {
                    float4 m4 = *(const float4*)(pm + (size_t)(d - 4) * PLANE);
                    float4 f4 = *(const float4*)(pf + (size_t)(d - 4) * PLANE);
                    ACC4(m4, f4, -=)
                }
            }
        }
        // ---- write burst phase (pure writes, 25 stores) ----
#pragma unroll
        for (int f = 0; f < 5; ++f) {
#pragma unroll
            for (int k = 0; k < BG; ++k) {
                const int d = c0 + g * BG + k;
                *(h4*)(fb + (size_t)f * VOL + (size_t)d * PLANE) = buf[k][f];
            }
        }
    }
#undef ACC4
}

// ---------------------------------------------------------------------------
// Pass 2: W+H box sums of the 5 D-summed fields + per-voxel cc + reduction.
// Stage B accumulates the 9-tap H-sum in PACKED fp16 (v_pk_add_f16) —
// converts to f32 only for the final cc math. Block: 512 thr. Grid (10,160,2).
// ---------------------------------------------------------------------------
__global__ __launch_bounds__(512, 6) void ncc_whcc(const _Float16* __restrict__ fields,
                                                   float* __restrict__ partial) {
    __shared__ _Float16 ws[5][HS][LDWH];
    __shared__ float red[8];

    const int hx  = blockIdx.x;        // 0..9
    const int d   = blockIdx.y;        // 0..159
    const int b   = blockIdx.z;        // 0..1
    const int h0  = hx * HT;
    const int tid = threadIdx.x;

    if (tid < 480) {
        const int r  = tid / 20;       // 0..23 staged row
        const int s  = tid - r * 20;   // 0..19 octet
        const int h  = h0 - 4 + r;
        const int w0 = 8 * s;
        const bool rowok = (unsigned)h < (unsigned)HH;

#pragma unroll
        for (int f = 0; f < 5; ++f) {
            float v[16];
#pragma unroll
            for (int i = 0; i < 16; ++i) v[i] = 0.f;
            if (rowok) {
                const _Float16* fr = fields + (size_t)(b * 5 + f) * VOL
                                            + ((size_t)d * HH + h) * WW;
                if (s > 0) {
                    h4 a = *(const h4*)(fr + w0 - 4);
                    v[0] = (float)a.x; v[1] = (float)a.y; v[2] = (float)a.z; v[3] = (float)a.w;
                }
                h4 a1 = *(const h4*)(fr + w0);
                v[4] = (float)a1.x; v[5] = (float)a1.y; v[6] = (float)a1.z; v[7] = (float)a1.w;
                h4 a2 = *(const h4*)(fr + w0 + 4);
                v[8] = (float)a2.x; v[9] = (float)a2.y; v[10] = (float)a2.z; v[11] = (float)a2.w;
                if (s < 19) {
                    h4 a3 = *(const h4*)(fr + w0 + 8);
                    v[12] = (float)a3.x; v[13] = (float)a3.y; v[14] = (float)a3.z; v[15] = (float)a3.w;
                }
            }
            float o[8];
            float sum = 0.f;
#pragma unroll
            for (int i = 0; i < 9; ++i) sum += v[i];
            o[0] = sum;
#pragma unroll
            for (int k = 1; k < 8; ++k) {
                sum += v[k + 8] - v[k - 1];
                o[k] = sum;
            }
            h8 pk;
#pragma unroll
            for (int j = 0; j < 8; ++j) pk[j] = (_Float16)o[j];
            *(h8*)&ws[f][r][w0] = pk;
        }
    }
    __syncthreads();

    float acc = 0.f;
    if (tid < 320) {
        const int ro  = tid / 20;      // 0..15 output row
        const int oct = tid - ro * 20; // 0..19
        const int w   = 8 * oct;

        // packed fp16 9-tap column sums (v_pk_add_f16)
        h8 a0 = *(const h8*)&ws[0][ro][w];
        h8 a1 = *(const h8*)&ws[1][ro][w];
        h8 a2 = *(const h8*)&ws[2][ro][w];
        h8 a3 = *(const h8*)&ws[3][ro][w];
        h8 a4 = *(const h8*)&ws[4][ro][w];
#pragma unroll
        for (int t = 1; t < 9; ++t) {
            a0 += *(const h8*)&ws[0][ro + t][w];
            a1 += *(const h8*)&ws[1][ro + t][w];
            a2 += *(const h8*)&ws[2][ro + t][w];
            a3 += *(const h8*)&ws[3][ro + t][w];
            a4 += *(const h8*)&ws[4][ro + t][w];
        }
        const float inv_win = 1.0f / 729.0f;
#pragma unroll
        for (int j = 0; j < 8; ++j) {
            float s0 = (float)a0[j], s1 = (float)a1[j];
            float s2 = (float)a2[j], s3 = (float)a3[j], s4 = (float)a4[j];
            float cross = fmaf(-(s0 * s1), inv_win, s4);
            float pv = fmaxf(fmaf(-(s0 * s0), inv_win, s2), 0.f);
            float tv = fmaxf(fmaf(-(s1 * s1), inv_win, s3), 0.f);
            float cc = cross * cross / (pv * tv + 0.001f);
            acc += fminf(fmaxf(cc, 0.f), 1.f);
        }
    }

    for (int o = 32; o > 0; o >>= 1) acc += __shfl_down(acc, o, 64);
    int lane = tid & 63, wid = tid >> 6;
    if (lane == 0) red[wid] = acc;
    __syncthreads();
    if (tid == 0) {
        float r8 = 0.f;
#pragma unroll
        for (int i = 0; i < 8; ++i) r8 += red[i];
        partial[((size_t)b * DD + d) * (HH / HT) + hx] = r8;
    }
}

// ---------------------------------------------------------------------------
// Pass 3: L1 gradient penalty — d-walking float4 chunks.
// ---------------------------------------------------------------------------
__global__ __launch_bounds__(256) void grad_red(const float* __restrict__ fl,
                                                float* __restrict__ partial) {
    const int gid = blockIdx.x * 256 + threadIdx.x;  // 0..307199
    const int w4  = gid % 40;
    int t = gid / 40;
    const int h  = t % HH;  t /= HH;
    const int dc = t % (DD / GCHD); t /= (DD / GCHD);
    const int bc = t;                                // 0..5
    const int d0 = dc * GCHD;
    const int w  = w4 * 4;

    const float* base = fl + (size_t)bc * VOL;
    float acc = 0.f;
    float4 v = *(const float4*)(base + ((size_t)d0 * HH + h) * WW + w);
    for (int d = d0; d < d0 + GCHD; ++d) {
        const float* pd = base + ((size_t)d * HH + h) * WW + w;
        float4 vn = v;
        if (d < DD - 1) {
            vn = *(const float4*)(pd + PLANE);
            acc += fabsf(vn.x - v.x) + fabsf(vn.y - v.y) +
                   fabsf(vn.z - v.z) + fabsf(vn.w - v.w);
        }
        if (h < HH - 1) {
            float4 vh = *(const float4*)(pd + WW);
            acc += fabsf(vh.x - v.x) + fabsf(vh.y - v.y) +
                   fabsf(vh.z - v.z) + fabsf(vh.w - v.w);
        }
        acc += fabsf(v.y - v.x) + fabsf(v.z - v.y) + fabsf(v.w - v.z);
        if (w < WW - 4) acc += fabsf(pd[4] - v.w);
        v = vn;
    }

    for (int o = 32; o > 0; o >>= 1) acc += __shfl_down(acc, o, 64);
    __shared__ float red[4];
    int lane = threadIdx.x & 63, wid = threadIdx.x >> 6;
    if (lane == 0) red[wid] = acc;
    __syncthreads();
    if (threadIdx.x == 0) partial[blockIdx.x] = red[0] + red[1] + red[2] + red[3];
}

// ---------------------------------------------------------------------------
// finalize: deterministic reduction of partials -> scalar loss
// ---------------------------------------------------------------------------
__global__ __launch_bounds__(256) void finalize(const float* __restrict__ pcc, int ncc,
                                                const float* __restrict__ pg, int ng,
                                                float* __restrict__ out) {
    __shared__ float red[4];
    int lane = threadIdx.x & 63, wid = threadIdx.x >> 6;

    float a = 0.f;
    for (int i = threadIdx.x; i < ncc; i += 256) a += pcc[i];
    for (int o = 32; o > 0; o >>= 1) a += __shfl_down(a, o, 64);
    if (lane == 0) red[wid] = a;
    __syncthreads();
    float asum = red[0] + red[1] + red[2] + red[3];
    __syncthreads();

    float g = 0.f;
    for (int i = threadIdx.x; i < ng; i += 256) g += pg[i];
    for (int o = 32; o > 0; o >>= 1) g += __shfl_down(g, o, 64);
    if (lane == 0) red[wid] = g;
    __syncthreads();
    float gsum = red[0] + red[1] + red[2] + red[3];

    if (threadIdx.x == 0) {
        float sim = 1.0f - asum / 8192000.0f;          // mean over (2,1,160,160,160)
        float reg = gsum / 73267200.0f;                // 3 * (2*3*159*160*160)
        out[0] = sim + reg;
    }
}

// ---------------------------------------------------------------------------
extern "C" void kernel_launch(void* const* d_in, const int* in_sizes, int n_in,
                              void* d_out, int out_size, void* d_ws, size_t ws_size,
                              hipStream_t stream) {
    const float* moved  = (const float*)d_in[0];
    const float* fixedp = (const float*)d_in[1];
    const float* flow   = (const float*)d_in[2];
    float* out = (float*)d_out;

    _Float16* fields = (_Float16*)d_ws;                   // NB*5*VOL fp16 SoA (81.9 MB)
    float* pcc = (float*)(fields + (size_t)NB * 5 * VOL); // WHBLK floats
    float* pg  = pcc + WHBLK;                             // GBLK floats

    dsum<<<NDSUM, 256, 0, stream>>>(moved, fixedp, fields);
    ncc_whcc<<<dim3(HH / HT, DD, NB), 512, 0, stream>>>(fields, pcc);
    grad_red<<<GBLK, 256, 0, stream>>>(flow, pg);
    finalize<<<1, 256, 0, stream>>>(pcc, WHBLK, pg, GBLK, out);
}